// Round 4
// baseline (367.755 us; speedup 1.0000x reference)
//
#include <hip/hip_runtime.h>

typedef __bf16 bf16x8 __attribute__((ext_vector_type(8)));
typedef __bf16 bf16x4 __attribute__((ext_vector_type(4)));
typedef float f32x4 __attribute__((ext_vector_type(4)));

#define GLOAD_LDS16(g, l)                                                      \
  __builtin_amdgcn_global_load_lds(                                            \
      (const __attribute__((address_space(1))) void*)(g),                      \
      (__attribute__((address_space(3))) void*)(l), 16, 0, 0)

// ---------------- K0: zero E/psum/cntv --------------------------------------
__global__ __launch_bounds__(256) void k_zero(float* __restrict__ E,
                                              float* __restrict__ psum,
                                              int* __restrict__ cntv, int Nv) {
  const int i = blockIdx.x * 256 + threadIdx.x;
  if (i < Nv) {
    E[i] = 0.f;
    psum[i] = 0.f;
  }
  if (i < 4) cntv[i] = 0;
}

// ---------------- K1: normalize rows -> bf16, build code[] + histogram ------
__global__ __launch_bounds__(128) void k_normalize(
    const float* __restrict__ X, const int* __restrict__ labels,
    const int* __restrict__ bad, __bf16* __restrict__ fn,
    unsigned char* __restrict__ code, int* __restrict__ cntv, int Dv) {
  const int row = blockIdx.x;
  const int t = threadIdx.x;
  const float4* xr = (const float4*)(X + (size_t)row * Dv);
  float ss = 0.f;
  const int nv4 = Dv >> 2;
  for (int idx = t; idx < nv4; idx += 128) {
    float4 v = xr[idx];
    ss += v.x * v.x + v.y * v.y + v.z * v.z + v.w * v.w;
  }
#pragma unroll
  for (int off = 32; off; off >>= 1) ss += __shfl_down(ss, off);
  __shared__ float sred[2];
  if ((t & 63) == 0) sred[t >> 6] = ss;
  __syncthreads();
  const float inv = 1.0f / sqrtf(sred[0] + sred[1]);
  for (int idx = t; idx < nv4; idx += 128) {
    float4 v = xr[idx];
    bf16x4 o;
    o.x = (__bf16)(v.x * inv);
    o.y = (__bf16)(v.y * inv);
    o.z = (__bf16)(v.z * inv);
    o.w = (__bf16)(v.w * inv);
    *(bf16x4*)(fn + (size_t)row * Dv + idx * 4) = o;
  }
  if (t == 0) {
    const bool valid = (bad[row] == 0);
    unsigned char c = valid ? (unsigned char)labels[row] : (unsigned char)255;
    code[row] = c;
    if (valid) atomicAdd(&cntv[c], 1);
  }
}

// Shared MFMA K-loop for both passes: computes the 128x128 tile (bi,bj) into
// acc[4][4] (4 waves x 64x64, 16x16x32 bf16 MFMA, BK=32 — stride-64B LDS rows
// are bank-friendly; BK=64's 128B stride halved bank utilization in R2).
// C/D layout (verified m89/m91): col = lane&15, row = quad*4 + reg.
__device__ __forceinline__ void tile_mm(const __bf16* __restrict__ fn, int Dv,
                                        size_t rowA, size_t rowB, __bf16* As,
                                        __bf16* Bs, f32x4 (&acc)[4][4]) {
  const int t = threadIdx.x;
  const int lane = t & 63;
  const int wave = t >> 6;
  const int quad = lane >> 4;
  const int l16 = lane & 15;
  const int wm = (wave >> 1) * 64;
  const int wn = (wave & 1) * 64;
  for (int k0 = 0; k0 < Dv; k0 += 32) {
#pragma unroll
    for (int it = 0; it < 2; ++it) {
      const int c = t + it * 256;  // chunk 0..511 ; chunk = 16B = 8 bf16
      const int r = c >> 2;
      const int q = c & 3;
      const __bf16* ga = fn + (rowA + r) * Dv + k0 + q * 8;
      const __bf16* gb = fn + (rowB + r) * Dv + k0 + q * 8;
      // LDS dest is wave-uniform base + lane*16 (HW behavior)
      __bf16* la = As + (size_t)(it * 256 + wave * 64) * 8;
      __bf16* lb = Bs + (size_t)(it * 256 + wave * 64) * 8;
      GLOAD_LDS16(ga, la);
      GLOAD_LDS16(gb, lb);
    }
    __syncthreads();
    bf16x8 af[4], bfv[4];
#pragma unroll
    for (int mi = 0; mi < 4; ++mi)
      af[mi] = *(const bf16x8*)(As + (wm + mi * 16 + l16) * 32 + quad * 8);
#pragma unroll
    for (int ni = 0; ni < 4; ++ni)
      bfv[ni] = *(const bf16x8*)(Bs + (wn + ni * 16 + l16) * 32 + quad * 8);
#pragma unroll
    for (int mi = 0; mi < 4; ++mi)
#pragma unroll
      for (int ni = 0; ni < 4; ++ni)
        acc[mi][ni] = __builtin_amdgcn_mfma_f32_16x16x32_bf16(
            af[mi], bfv[ni], acc[mi][ni], 0, 0, 0);
    __syncthreads();
  }
}

__device__ __forceinline__ void tri_decode(int blk, int NT, int& bi, int& bj) {
  int b = 0, rem = blk, span = NT;
  while (rem >= span) {
    rem -= span;
    b++;
    span--;
  }
  bi = b;
  bj = b + rem;
}

// ---------------- K2a: pass 1 — E_i = sum_neg exp(S_ij), fused --------------
__global__ __launch_bounds__(256) void k_p1(const __bf16* __restrict__ fn,
                                            const unsigned char* __restrict__
                                                code,
                                            float* __restrict__ E, int Nv,
                                            int Dv) {
  __shared__ __align__(16) __bf16 As[128 * 32];
  __shared__ __align__(16) __bf16 Bs[128 * 32];
  __shared__ unsigned char cA[128], cB[128];
  const int NT = Nv >> 7;
  int bi, bj;
  tri_decode(blockIdx.x, NT, bi, bj);
  const size_t rowA = (size_t)bi * 128;
  const size_t rowB = (size_t)bj * 128;
  const int t = threadIdx.x;
  if (t < 128)
    cA[t] = code[rowA + t];
  else
    cB[t - 128] = code[rowB + t - 128];

  f32x4 acc[4][4] = {};
  tile_mm(fn, Dv, rowA, rowB, As, Bs, acc);

  const int lane = t & 63;
  const int wave = t >> 6;
  const int quad = lane >> 4;
  const int l16 = lane & 15;
  const int wm = (wave >> 1) * 64;
  const int wn = (wave & 1) * 64;

  unsigned char ca[16], cb[4];
#pragma unroll
  for (int mi = 0; mi < 4; ++mi)
#pragma unroll
    for (int r = 0; r < 4; ++r) ca[mi * 4 + r] = cA[wm + mi * 16 + quad * 4 + r];
#pragma unroll
  for (int ni = 0; ni < 4; ++ni) cb[ni] = cB[wn + ni * 16 + l16];

  float rowsum[16] = {};
  float colsum[4] = {};
#pragma unroll
  for (int mi = 0; mi < 4; ++mi)
#pragma unroll
    for (int ni = 0; ni < 4; ++ni)
#pragma unroll
      for (int r = 0; r < 4; ++r) {
        const float ex = __expf(acc[mi][ni][r] * 10.0f);
        const int a = ca[mi * 4 + r], b = cb[ni];
        const bool diff = a != b;
        rowsum[mi * 4 + r] += (b <= 2 && diff) ? ex : 0.f;
        colsum[ni] += (a <= 2 && diff) ? ex : 0.f;
      }
  // row-sums: reduce across the 16 l16 lanes (same quad)
#pragma unroll
  for (int off = 1; off < 16; off <<= 1)
#pragma unroll
    for (int k = 0; k < 16; ++k) rowsum[k] += __shfl_xor(rowsum[k], off);
  if (l16 == 0)
#pragma unroll
    for (int k = 0; k < 16; ++k)
      atomicAdd(&E[rowA + wm + (k >> 2) * 16 + quad * 4 + (k & 3)], rowsum[k]);
  if (bi != bj) {
    // col-sums: reduce across the 4 quads (xor 16, 32)
#pragma unroll
    for (int off = 16; off < 64; off <<= 1)
#pragma unroll
      for (int ni = 0; ni < 4; ++ni) colsum[ni] += __shfl_xor(colsum[ni], off);
    if (quad == 0)
#pragma unroll
      for (int ni = 0; ni < 4; ++ni)
        atomicAdd(&E[rowB + wn + ni * 16 + l16], colsum[ni]);
  }
}

// ---------------- K2b: pass 2 — psum_i = sum_pos log1p(E_i exp(-S_ip)) -----
__global__ __launch_bounds__(256) void k_p2(const __bf16* __restrict__ fn,
                                            const unsigned char* __restrict__
                                                code,
                                            const float* __restrict__ E,
                                            float* __restrict__ psum, int Nv,
                                            int Dv) {
  __shared__ __align__(16) __bf16 As[128 * 32];
  __shared__ __align__(16) __bf16 Bs[128 * 32];
  __shared__ unsigned char cA[128], cB[128];
  __shared__ float eAs[128], eBs[128];
  const int NT = Nv >> 7;
  int bi, bj;
  tri_decode(blockIdx.x, NT, bi, bj);
  const size_t rowA = (size_t)bi * 128;
  const size_t rowB = (size_t)bj * 128;
  const int t = threadIdx.x;
  if (t < 128) {
    cA[t] = code[rowA + t];
    eAs[t] = E[rowA + t];
  } else {
    cB[t - 128] = code[rowB + t - 128];
    eBs[t - 128] = E[rowB + t - 128];
  }

  f32x4 acc[4][4] = {};
  tile_mm(fn, Dv, rowA, rowB, As, Bs, acc);

  const int lane = t & 63;
  const int wave = t >> 6;
  const int quad = lane >> 4;
  const int l16 = lane & 15;
  const int wm = (wave >> 1) * 64;
  const int wn = (wave & 1) * 64;

  unsigned char ca[16], cb[4];
  float eAr[16], eBc[4];
#pragma unroll
  for (int mi = 0; mi < 4; ++mi)
#pragma unroll
    for (int r = 0; r < 4; ++r) {
      const int rl = wm + mi * 16 + quad * 4 + r;
      ca[mi * 4 + r] = cA[rl];
      eAr[mi * 4 + r] = eAs[rl];
    }
#pragma unroll
  for (int ni = 0; ni < 4; ++ni) {
    const int cl = wn + ni * 16 + l16;
    cb[ni] = cB[cl];
    eBc[ni] = eBs[cl];
  }

  const bool diag = (bi == bj);
  float rowsum[16] = {};
  float colsum[4] = {};
#pragma unroll
  for (int mi = 0; mi < 4; ++mi)
#pragma unroll
    for (int ni = 0; ni < 4; ++ni)
#pragma unroll
      for (int r = 0; r < 4; ++r) {
        const int k = mi * 4 + r;
        const float em = __expf(-acc[mi][ni][r] * 10.0f);
        const int a = ca[k], b = cb[ni];
        const bool self =
            diag && (wm + mi * 16 + quad * 4 + r) == (wn + ni * 16 + l16);
        const bool pos = (a == b) && (b <= 2) && !self;
        // x in [~1e-13, ~2e12]: __logf(1+x) abs err < 1e-6 at tiny x — fine
        rowsum[k] += pos ? __logf(1.f + eAr[k] * em) : 0.f;
        colsum[ni] += pos ? __logf(1.f + eBc[ni] * em) : 0.f;
      }
#pragma unroll
  for (int off = 1; off < 16; off <<= 1)
#pragma unroll
    for (int k = 0; k < 16; ++k) rowsum[k] += __shfl_xor(rowsum[k], off);
  if (l16 == 0)
#pragma unroll
    for (int k = 0; k < 16; ++k)
      atomicAdd(&psum[rowA + wm + (k >> 2) * 16 + quad * 4 + (k & 3)],
                rowsum[k]);
  if (!diag) {
#pragma unroll
    for (int off = 16; off < 64; off <<= 1)
#pragma unroll
      for (int ni = 0; ni < 4; ++ni) colsum[ni] += __shfl_xor(colsum[ni], off);
    if (quad == 0)
#pragma unroll
      for (int ni = 0; ni < 4; ++ni)
        atomicAdd(&psum[rowB + wn + ni * 16 + l16], colsum[ni]);
  }
}

// ---------------- K4: final deterministic reduce ----------------------------
__global__ __launch_bounds__(256) void k_final(
    const float* __restrict__ psum, const float* __restrict__ E,
    const unsigned char* __restrict__ code, const int* __restrict__ cntv,
    float* __restrict__ out, int Nv) {
  const int t = threadIdx.x;
  const int c0 = cntv[0], c1 = cntv[1], c2 = cntv[2];
  const int validTotal = c0 + c1 + c2;
  const float em10 = __expf(-10.0f);
  double s = 0.0;
  int c = 0;
  for (int i = t; i < Nv; i += 256) {
    const int myc = code[i];
    if (myc > 2) continue;  // invalid anchor
    const int cmy = (myc == 0) ? c0 : ((myc == 1) ? c1 : c2);
    if (validTotal - cmy == 0) continue;  // no negatives
    const int pos_cnt = cmy - 1;
    if (pos_cnt > 0) {
      s += (double)(psum[i] / (float)pos_cnt);
      c += 1;
    } else {
      s += (double)__logf(1.f + E[i] * em10);  // logaddexp(1/T,lse) - 1/T
    }
  }
#pragma unroll
  for (int off = 32; off; off >>= 1) {
    s += __shfl_down(s, off);
    c += __shfl_down(c, off);
  }
  __shared__ double sd[4];
  __shared__ int si[4];
  if ((t & 63) == 0) {
    sd[t >> 6] = s;
    si[t >> 6] = c;
  }
  __syncthreads();
  if (t == 0) {
    const double st = sd[0] + sd[1] + sd[2] + sd[3];
    const int ct = 1 + si[0] + si[1] + si[2] + si[3];
    out[0] = (float)(st / (double)ct);
  }
}

extern "C" void kernel_launch(void* const* d_in, const int* in_sizes, int n_in,
                              void* d_out, int out_size, void* d_ws,
                              size_t ws_size, hipStream_t stream) {
  const float* X = (const float*)d_in[0];
  const int* labels = (const int*)d_in[1];
  const int* bad = (const int*)d_in[2];
  const int Nv = in_sizes[1];
  const int Dv = in_sizes[0] / Nv;

  size_t off = 0;
  auto alloc = [&](size_t bytes) -> void* {
    size_t p = (off + 255) & ~(size_t)255;
    off = p + bytes;
    return (void*)((char*)d_ws + p);
  };
  __bf16* fn = (__bf16*)alloc((size_t)Nv * Dv * 2);
  float* E = (float*)alloc((size_t)Nv * 4);
  float* psum = (float*)alloc((size_t)Nv * 4);
  unsigned char* code = (unsigned char*)alloc((size_t)Nv);
  int* cntv = (int*)alloc(16);
  if (off > ws_size) return;  // scratch too small: fail loudly at validation

  k_zero<<<(Nv + 255) / 256, 256, 0, stream>>>(E, psum, cntv, Nv);
  k_normalize<<<Nv, 128, 0, stream>>>(X, labels, bad, fn, code, cntv, Dv);
  const int NT = Nv / 128;
  const int ntri = NT * (NT + 1) / 2;
  k_p1<<<ntri, 256, 0, stream>>>(fn, code, E, Nv, Dv);
  k_p2<<<ntri, 256, 0, stream>>>(fn, code, E, psum, Nv, Dv);
  k_final<<<1, 256, 0, stream>>>(psum, E, code, cntv, (float*)d_out, Nv);
}

// Round 6
// 182.972 us; speedup vs baseline: 2.0099x; 2.0099x over previous
//
#include <hip/hip_runtime.h>

typedef __bf16 bf16x8 __attribute__((ext_vector_type(8)));
typedef __bf16 bf16x4 __attribute__((ext_vector_type(4)));
typedef float f32x4 __attribute__((ext_vector_type(4)));

#define GLOAD_LDS16(g, l)                                                      \
  __builtin_amdgcn_global_load_lds(                                            \
      (const __attribute__((address_space(1))) void*)(g),                      \
      (__attribute__((address_space(3))) void*)(l), 16, 0, 0)

// ---------------- K1: codes + stable label-partition scan (1 block) ---------
// dst[r] = gathered index for valid rows, grouped by label (0,1,2 ascending),
// stable within label. hdr = {M, Mpad, NTv, ntri, C0, C1, C2}.
__global__ __launch_bounds__(1024) void k_scan(const int* __restrict__ labels,
                                               const int* __restrict__ bad,
                                               unsigned char* __restrict__ code,
                                               int* __restrict__ dst,
                                               int* __restrict__ hdr, int Nv) {
  const int t = threadIdx.x;
  const int per = Nv >> 10;  // rows per thread (8 for 8192)
  const int base = t * per;
  unsigned char lc[8];
  int cnt[3] = {0, 0, 0};
  for (int k = 0; k < per; ++k) {
    const int r = base + k;
    const unsigned char c =
        (bad[r] == 0) ? (unsigned char)labels[r] : (unsigned char)255;
    lc[k] = c;
    code[r] = c;
    if (c <= 2) cnt[c]++;
  }
  __shared__ int s0[1024], s1[1024], s2[1024];
  s0[t] = cnt[0];
  s1[t] = cnt[1];
  s2[t] = cnt[2];
  __syncthreads();
  for (int off = 1; off < 1024; off <<= 1) {
    const int a0 = (t >= off) ? s0[t - off] : 0;
    const int a1 = (t >= off) ? s1[t - off] : 0;
    const int a2 = (t >= off) ? s2[t - off] : 0;
    __syncthreads();
    s0[t] += a0;
    s1[t] += a1;
    s2[t] += a2;
    __syncthreads();
  }
  const int C0 = s0[1023], C1 = s1[1023], C2 = s2[1023];
  int run[3];
  run[0] = s0[t] - cnt[0];
  run[1] = C0 + s1[t] - cnt[1];
  run[2] = C0 + C1 + s2[t] - cnt[2];
  for (int k = 0; k < per; ++k) {
    const int c = lc[k];
    dst[base + k] = (c <= 2) ? run[c]++ : -1;
  }
  if (t == 0) {
    const int M = C0 + C1 + C2;
    const int Mpad = (M + 127) & ~127;
    const int NTv = Mpad >> 7;
    hdr[0] = M;
    hdr[1] = Mpad;
    hdr[2] = NTv;
    hdr[3] = NTv * (NTv + 1) / 2;
    hdr[4] = C0;
    hdr[5] = C1;
    hdr[6] = C2;
  }
}

// ---------------- K2: normalize valid rows -> bf16, gathered+sorted ---------
__global__ __launch_bounds__(128) void k_norm(const float* __restrict__ X,
                                              const unsigned char* __restrict__
                                                  code,
                                              const int* __restrict__ dst,
                                              __bf16* __restrict__ fng,
                                              unsigned char* __restrict__ gcode,
                                              int Dv) {
  const int row = blockIdx.x;
  const unsigned char c = code[row];
  if (c > 2) return;  // invalid: skipped entirely
  const int g = dst[row];
  const int t = threadIdx.x;
  const float4* xr = (const float4*)(X + (size_t)row * Dv);
  float ss = 0.f;
  const int nv4 = Dv >> 2;
  for (int idx = t; idx < nv4; idx += 128) {
    float4 v = xr[idx];
    ss += v.x * v.x + v.y * v.y + v.z * v.z + v.w * v.w;
  }
#pragma unroll
  for (int off = 32; off; off >>= 1) ss += __shfl_down(ss, off);
  __shared__ float sred[2];
  if ((t & 63) == 0) sred[t >> 6] = ss;
  __syncthreads();
  const float inv = 1.0f / sqrtf(sred[0] + sred[1]);
  for (int idx = t; idx < nv4; idx += 128) {
    float4 v = xr[idx];
    bf16x4 o;
    o.x = (__bf16)(v.x * inv);
    o.y = (__bf16)(v.y * inv);
    o.z = (__bf16)(v.z * inv);
    o.w = (__bf16)(v.w * inv);
    *(bf16x4*)(fng + (size_t)g * Dv + idx * 4) = o;
  }
  if (t == 0) gcode[g] = c;
}

// Shared MFMA K-loop: 128x128 tile, BK=32 (stride-64B LDS rows, bank-friendly),
// 4 waves x 64x64 via 4x4 of 16x16x32 bf16 MFMA.
// C/D layout (verified m89/m91): col = lane&15, row = quad*4 + reg.
__device__ __forceinline__ void tile_mm(const __bf16* __restrict__ fn, int Dv,
                                        size_t rowA, size_t rowB, __bf16* As,
                                        __bf16* Bs, f32x4 (&acc)[4][4]) {
  const int t = threadIdx.x;
  const int lane = t & 63;
  const int wave = t >> 6;
  const int quad = lane >> 4;
  const int l16 = lane & 15;
  const int wm = (wave >> 1) * 64;
  const int wn = (wave & 1) * 64;
  for (int k0 = 0; k0 < Dv; k0 += 32) {
#pragma unroll
    for (int it = 0; it < 2; ++it) {
      const int c = t + it * 256;  // chunk 0..511 ; chunk = 16B = 8 bf16
      const int r = c >> 2;
      const int q = c & 3;
      const __bf16* ga = fn + (rowA + r) * Dv + k0 + q * 8;
      const __bf16* gb = fn + (rowB + r) * Dv + k0 + q * 8;
      __bf16* la = As + (size_t)(it * 256 + wave * 64) * 8;
      __bf16* lb = Bs + (size_t)(it * 256 + wave * 64) * 8;
      GLOAD_LDS16(ga, la);
      GLOAD_LDS16(gb, lb);
    }
    __syncthreads();
    bf16x8 af[4], bfv[4];
#pragma unroll
    for (int mi = 0; mi < 4; ++mi)
      af[mi] = *(const bf16x8*)(As + (wm + mi * 16 + l16) * 32 + quad * 8);
#pragma unroll
    for (int ni = 0; ni < 4; ++ni)
      bfv[ni] = *(const bf16x8*)(Bs + (wn + ni * 16 + l16) * 32 + quad * 8);
#pragma unroll
    for (int mi = 0; mi < 4; ++mi)
#pragma unroll
      for (int ni = 0; ni < 4; ++ni)
        acc[mi][ni] = __builtin_amdgcn_mfma_f32_16x16x32_bf16(
            af[mi], bfv[ni], acc[mi][ni], 0, 0, 0);
    __syncthreads();
  }
}

__device__ __forceinline__ void tri_decode(int blk, int NT, int& bi, int& bj) {
  int b = 0, rem = blk, span = NT;
  while (rem >= span) {
    rem -= span;
    b++;
    span--;
  }
  bi = b;
  bj = b + rem;
}

// ---------------- K3: pass 1 — per-tile exp-sums into HALF-slot partials ----
// Two waves cover the same rows (split by column-half) and two waves cover the
// same columns (split by row-half) — so each (row, tile, side) gets TWO slots:
//   A-side (rows of block bi): slot = bj*2 + (wave&1)   [column half]
//   B-side (cols of block bj): slot = bi*2 + (wave>>1)  [row half]
// Every slot [0, 2*NTv) of every gathered row written exactly once: no atomics.
__global__ __launch_bounds__(256) void k_p1(const __bf16* __restrict__ fng,
                                            const unsigned char* __restrict__
                                                gcode,
                                            const int* __restrict__ hdr,
                                            float* __restrict__ P, int Dv) {
  const int NTv = hdr[2];
  if ((int)blockIdx.x >= hdr[3]) return;
  int bi, bj;
  tri_decode(blockIdx.x, NTv, bi, bj);
  const size_t rowA = (size_t)bi * 128;
  const size_t rowB = (size_t)bj * 128;
  __shared__ __align__(16) __bf16 As[128 * 32];
  __shared__ __align__(16) __bf16 Bs[128 * 32];
  __shared__ unsigned char cA[128], cB[128];
  const int t = threadIdx.x;
  if (t < 128)
    cA[t] = gcode[rowA + t];
  else
    cB[t - 128] = gcode[rowB + t - 128];

  f32x4 acc[4][4] = {};
  tile_mm(fng, Dv, rowA, rowB, As, Bs, acc);

  const int lane = t & 63;
  const int wave = t >> 6;
  const int quad = lane >> 4;
  const int l16 = lane & 15;
  const int wm = (wave >> 1) * 64;
  const int wn = (wave & 1) * 64;

  unsigned char ca[16], cb[4];
#pragma unroll
  for (int mi = 0; mi < 4; ++mi)
#pragma unroll
    for (int r = 0; r < 4; ++r) ca[mi * 4 + r] = cA[wm + mi * 16 + quad * 4 + r];
#pragma unroll
  for (int ni = 0; ni < 4; ++ni) cb[ni] = cB[wn + ni * 16 + l16];

  float rowsum[16] = {};
  float colsum[4] = {};
#pragma unroll
  for (int mi = 0; mi < 4; ++mi)
#pragma unroll
    for (int ni = 0; ni < 4; ++ni)
#pragma unroll
      for (int r = 0; r < 4; ++r) {
        const float ex = __expf(acc[mi][ni][r] * 10.0f);
        const int a = ca[mi * 4 + r], b = cb[ni];
        const bool diff = a != b;
        rowsum[mi * 4 + r] += (b <= 2 && diff) ? ex : 0.f;
        colsum[ni] += (a <= 2 && diff) ? ex : 0.f;
      }
#pragma unroll
  for (int off = 1; off < 16; off <<= 1)
#pragma unroll
    for (int k = 0; k < 16; ++k) rowsum[k] += __shfl_xor(rowsum[k], off);
  if (l16 == 0)
#pragma unroll
    for (int k = 0; k < 16; ++k)
      P[(size_t)(rowA + wm + (k >> 2) * 16 + quad * 4 + (k & 3)) * 128 +
        bj * 2 + (wave & 1)] = rowsum[k];
  if (bi != bj) {
#pragma unroll
    for (int off = 16; off < 64; off <<= 1)
#pragma unroll
      for (int ni = 0; ni < 4; ++ni) colsum[ni] += __shfl_xor(colsum[ni], off);
    if (quad == 0)
#pragma unroll
      for (int ni = 0; ni < 4; ++ni)
        P[(size_t)(rowB + wn + ni * 16 + l16) * 128 + bi * 2 + (wave >> 1)] =
            colsum[ni];
  }
}

// ---------------- K4: slot reduce: out[g] = sum_{slot<2*NTv} P[g*128+slot] --
__global__ __launch_bounds__(256) void k_red(const float* __restrict__ P,
                                             float* __restrict__ out,
                                             const int* __restrict__ hdr,
                                             int Nv) {
  const int g = blockIdx.x * 256 + threadIdx.x;
  if (g >= Nv) return;
  const int ns = hdr[2] * 2;
  float s = 0.f;
  const float4* p = (const float4*)(P + (size_t)g * 128);
  for (int k = 0; k < (ns >> 2); ++k) {
    const float4 v = p[k];
    s += v.x + v.y + v.z + v.w;
  }
  for (int k = ns & ~3; k < ns; ++k) s += P[(size_t)g * 128 + k];
  out[g] = s;
}

// ---------------- K5: pass 2 — positive log-terms into half-slot partials ---
// Rows are label-sorted, so tiles with no label overlap have no positives:
// they write zero slots and exit BEFORE staging (~2/3 of tiles).
__global__ __launch_bounds__(256) void k_p2(const __bf16* __restrict__ fng,
                                            const unsigned char* __restrict__
                                                gcode,
                                            const int* __restrict__ hdr,
                                            const float* __restrict__ E,
                                            float* __restrict__ P2, int Dv) {
  const int NTv = hdr[2];
  if ((int)blockIdx.x >= hdr[3]) return;
  int bi, bj;
  tri_decode(blockIdx.x, NTv, bi, bj);
  const size_t rowA = (size_t)bi * 128;
  const size_t rowB = (size_t)bj * 128;
  const int t = threadIdx.x;

  const int la0 = gcode[rowA], la1 = gcode[rowA + 127];
  const int lb0 = gcode[rowB], lb1 = gcode[rowB + 127];
  const int hiA = la1 > 2 ? 2 : la1;
  const int hiB = lb1 > 2 ? 2 : lb1;
  const int lo = la0 > lb0 ? la0 : lb0;
  const int hi = hiA < hiB ? hiA : hiB;
  const bool work = (la0 <= 2) && (lb0 <= 2) && (lo <= hi);
  if (!work) {
    if (t < 128) {
      P2[(size_t)(rowA + t) * 128 + bj * 2] = 0.f;
      P2[(size_t)(rowA + t) * 128 + bj * 2 + 1] = 0.f;
    } else if (bi != bj) {
      P2[(size_t)(rowB + t - 128) * 128 + bi * 2] = 0.f;
      P2[(size_t)(rowB + t - 128) * 128 + bi * 2 + 1] = 0.f;
    }
    return;
  }

  __shared__ __align__(16) __bf16 As[128 * 32];
  __shared__ __align__(16) __bf16 Bs[128 * 32];
  __shared__ unsigned char cA[128], cB[128];
  __shared__ float eAs[128], eBs[128];
  if (t < 128) {
    cA[t] = gcode[rowA + t];
    eAs[t] = E[rowA + t];
  } else {
    cB[t - 128] = gcode[rowB + t - 128];
    eBs[t - 128] = E[rowB + t - 128];
  }

  f32x4 acc[4][4] = {};
  tile_mm(fng, Dv, rowA, rowB, As, Bs, acc);

  const int lane = t & 63;
  const int wave = t >> 6;
  const int quad = lane >> 4;
  const int l16 = lane & 15;
  const int wm = (wave >> 1) * 64;
  const int wn = (wave & 1) * 64;

  unsigned char ca[16], cb[4];
  float eAr[16], eBc[4];
#pragma unroll
  for (int mi = 0; mi < 4; ++mi)
#pragma unroll
    for (int r = 0; r < 4; ++r) {
      const int rl = wm + mi * 16 + quad * 4 + r;
      ca[mi * 4 + r] = cA[rl];
      eAr[mi * 4 + r] = eAs[rl];
    }
#pragma unroll
  for (int ni = 0; ni < 4; ++ni) {
    const int cl = wn + ni * 16 + l16;
    cb[ni] = cB[cl];
    eBc[ni] = eBs[cl];
  }

  const bool diag = (bi == bj);
  float rowsum[16] = {};
  float colsum[4] = {};
#pragma unroll
  for (int mi = 0; mi < 4; ++mi)
#pragma unroll
    for (int ni = 0; ni < 4; ++ni)
#pragma unroll
      for (int r = 0; r < 4; ++r) {
        const int k = mi * 4 + r;
        const float em = __expf(-acc[mi][ni][r] * 10.0f);
        const int a = ca[k], b = cb[ni];
        const bool self =
            diag && (wm + mi * 16 + quad * 4 + r) == (wn + ni * 16 + l16);
        const bool pos = (a == b) && (b <= 2) && !self;
        rowsum[k] += pos ? __logf(1.f + eAr[k] * em) : 0.f;
        colsum[ni] += pos ? __logf(1.f + eBc[ni] * em) : 0.f;
      }
#pragma unroll
  for (int off = 1; off < 16; off <<= 1)
#pragma unroll
    for (int k = 0; k < 16; ++k) rowsum[k] += __shfl_xor(rowsum[k], off);
  if (l16 == 0)
#pragma unroll
    for (int k = 0; k < 16; ++k)
      P2[(size_t)(rowA + wm + (k >> 2) * 16 + quad * 4 + (k & 3)) * 128 +
         bj * 2 + (wave & 1)] = rowsum[k];
  if (!diag) {
#pragma unroll
    for (int off = 16; off < 64; off <<= 1)
#pragma unroll
      for (int ni = 0; ni < 4; ++ni) colsum[ni] += __shfl_xor(colsum[ni], off);
    if (quad == 0)
#pragma unroll
      for (int ni = 0; ni < 4; ++ni)
        P2[(size_t)(rowB + wn + ni * 16 + l16) * 128 + bi * 2 + (wave >> 1)] =
            colsum[ni];
  }
}

// ---------------- K6: final deterministic reduce ----------------------------
__global__ __launch_bounds__(256) void k_final(
    const float* __restrict__ psum, const float* __restrict__ E,
    const unsigned char* __restrict__ code, const int* __restrict__ dst,
    const int* __restrict__ hdr, float* __restrict__ out, int Nv) {
  const int t = threadIdx.x;
  const int c0 = hdr[4], c1 = hdr[5], c2 = hdr[6];
  const int validTotal = c0 + c1 + c2;
  const float em10 = __expf(-10.0f);
  double s = 0.0;
  int c = 0;
  for (int i = t; i < Nv; i += 256) {
    const int myc = code[i];
    if (myc > 2) continue;  // invalid anchor: not processed
    const int cmy = (myc == 0) ? c0 : ((myc == 1) ? c1 : c2);
    if (validTotal - cmy == 0) continue;  // no negatives: not processed
    const int g = dst[i];
    const int pos_cnt = cmy - 1;
    if (pos_cnt > 0) {
      s += (double)(psum[g] / (float)pos_cnt);
      c += 1;
    } else {
      s += (double)__logf(1.f + E[g] * em10);  // logaddexp(1/T,lse) - 1/T
    }
  }
#pragma unroll
  for (int off = 32; off; off >>= 1) {
    s += __shfl_down(s, off);
    c += __shfl_down(c, off);
  }
  __shared__ double sd[4];
  __shared__ int si[4];
  if ((t & 63) == 0) {
    sd[t >> 6] = s;
    si[t >> 6] = c;
  }
  __syncthreads();
  if (t == 0) {
    const double st = sd[0] + sd[1] + sd[2] + sd[3];
    const int ct = 1 + si[0] + si[1] + si[2] + si[3];
    out[0] = (float)(st / (double)ct);
  }
}

extern "C" void kernel_launch(void* const* d_in, const int* in_sizes, int n_in,
                              void* d_out, int out_size, void* d_ws,
                              size_t ws_size, hipStream_t stream) {
  const float* X = (const float*)d_in[0];
  const int* labels = (const int*)d_in[1];
  const int* bad = (const int*)d_in[2];
  const int Nv = in_sizes[1];
  const int Dv = in_sizes[0] / Nv;

  size_t off = 0;
  auto alloc = [&](size_t bytes) -> void* {
    size_t p = (off + 255) & ~(size_t)255;
    off = p + bytes;
    return (void*)((char*)d_ws + p);
  };
  __bf16* fng = (__bf16*)alloc((size_t)Nv * Dv * 2);
  float* P = (float*)alloc((size_t)Nv * 128 * 4);
  float* P2 = (float*)alloc((size_t)Nv * 128 * 4);
  float* E = (float*)alloc((size_t)Nv * 4);
  float* psum = (float*)alloc((size_t)Nv * 4);
  int* dst = (int*)alloc((size_t)Nv * 4);
  unsigned char* code = (unsigned char*)alloc((size_t)Nv);
  unsigned char* gcode = (unsigned char*)alloc((size_t)Nv);
  int* hdr = (int*)alloc(64);
  if (off > ws_size) return;  // scratch too small: fail loudly at validation

  // pad rows must be zero (MFMA reads them) and pad codes 255 (self-masking)
  hipMemsetAsync(fng, 0, (size_t)Nv * Dv * 2, stream);
  hipMemsetAsync(gcode, 0xFF, (size_t)Nv, stream);

  k_scan<<<1, 1024, 0, stream>>>(labels, bad, code, dst, hdr, Nv);
  k_norm<<<Nv, 128, 0, stream>>>(X, code, dst, fng, gcode, Dv);
  const int NT = Nv / 128;
  const int ntri_max = NT * (NT + 1) / 2;
  k_p1<<<ntri_max, 256, 0, stream>>>(fng, gcode, hdr, P, Dv);
  k_red<<<(Nv + 255) / 256, 256, 0, stream>>>(P, E, hdr, Nv);
  k_p2<<<ntri_max, 256, 0, stream>>>(fng, gcode, hdr, E, P2, Dv);
  k_red<<<(Nv + 255) / 256, 256, 0, stream>>>(P2, psum, hdr, Nv);
  k_final<<<1, 256, 0, stream>>>(psum, E, code, dst, hdr, (float*)d_out, Nv);
}